// Round 1
// baseline (88.309 us; speedup 1.0000x reference)
//
#include <hip/hip_runtime.h>
#include <math.h>

#define N 512
#define D 256
#define NUM_MARGIN 0.3f

// Kernel 1: one block per anchor row i. 256 threads, each handles 2 columns j.
__global__ __launch_bounds__(256) void triplet_rows_kernel(
    const float* __restrict__ X,   // (512, 256) fp32
    const int*  __restrict__ tgt,  // (512,) int32
    float* __restrict__ ws)        // (512,) per-row relu(ap - an + margin)
{
    const int i = blockIdx.x;   // 0..511
    const int t = threadIdx.x;  // 0..255

    __shared__ float xi[D];
    __shared__ int   tgts[N];

    xi[t] = X[i * D + t];
    tgts[t]       = tgt[t];
    tgts[t + 256] = tgt[t + 256];
    __syncthreads();

    const int ti = tgts[i];

    float ap = -INFINITY;  // hardest positive (max over same-class)
    float an =  INFINITY;  // hardest negative (min over diff-class)

    const float4* xiv = (const float4*)xi;

    #pragma unroll
    for (int jj = 0; jj < 2; ++jj) {
        const int j = t + jj * 256;
        const float4* xjv = (const float4*)(X + j * D);
        float s0 = 0.f, s1 = 0.f, s2 = 0.f, s3 = 0.f;
        #pragma unroll 16
        for (int d = 0; d < D / 4; ++d) {
            float4 a = xiv[d];          // same addr across wave -> LDS broadcast
            float4 b = xjv[d];          // coalesced-ish, L2-resident
            s0 += fabsf(a.x - b.x);
            s1 += fabsf(a.y - b.y);
            s2 += fabsf(a.z - b.z);
            s3 += fabsf(a.w - b.w);
        }
        const float dist = (s0 + s1 + s2 + s3) * (1.0f / (float)D);
        if (tgts[j] == ti) ap = fmaxf(ap, dist);
        else               an = fminf(an, dist);
    }

    // Wave-level reduction (wave = 64 lanes)
    #pragma unroll
    for (int off = 32; off >= 1; off >>= 1) {
        ap = fmaxf(ap, __shfl_down(ap, off, 64));
        an = fminf(an, __shfl_down(an, off, 64));
    }

    __shared__ float sap[4], san[4];
    if ((t & 63) == 0) { sap[t >> 6] = ap; san[t >> 6] = an; }
    __syncthreads();

    if (t == 0) {
        float a0 = fmaxf(fmaxf(sap[0], sap[1]), fmaxf(sap[2], sap[3]));
        float n0 = fminf(fminf(san[0], san[1]), fminf(san[2], san[3]));
        ws[i] = fmaxf(a0 - n0 + NUM_MARGIN, 0.0f);
    }
}

// Kernel 2: single block, 512 threads — mean over the 512 per-row losses.
__global__ __launch_bounds__(512) void triplet_reduce_kernel(
    const float* __restrict__ ws, float* __restrict__ out)
{
    const int t = threadIdx.x;  // 0..511
    float v = ws[t];
    #pragma unroll
    for (int off = 32; off >= 1; off >>= 1) v += __shfl_down(v, off, 64);
    __shared__ float s[8];
    if ((t & 63) == 0) s[t >> 6] = v;
    __syncthreads();
    if (t == 0) {
        float tot = 0.f;
        #pragma unroll
        for (int w = 0; w < 8; ++w) tot += s[w];
        out[0] = tot * (1.0f / (float)N);
    }
}

extern "C" void kernel_launch(void* const* d_in, const int* in_sizes, int n_in,
                              void* d_out, int out_size, void* d_ws, size_t ws_size,
                              hipStream_t stream) {
    const float* X   = (const float*)d_in[0];
    const int*   tgt = (const int*)d_in[1];
    float* out = (float*)d_out;
    float* ws  = (float*)d_ws;

    triplet_rows_kernel<<<N, 256, 0, stream>>>(X, tgt, ws);
    triplet_reduce_kernel<<<1, N, 0, stream>>>(ws, out);
}

// Round 2
// 63.108 us; speedup vs baseline: 1.3993x; 1.3993x over previous
//
#include <hip/hip_runtime.h>
#include <math.h>

#define N 512
#define D 256
#define LOSS_MARGIN 0.3f
#define TI 16
#define TJ 32
#define STRIDE 260   // 256 + 4 floats: keeps 16B alignment; worst LDS conflict = 2-way (free)

// Kernel 1: block = 16 anchors x 32 candidates tile. Grid (32, 16) = 512 blocks.
__global__ __launch_bounds__(256) void triplet_tile_kernel(
    const float* __restrict__ X,    // (512, 256)
    const int*  __restrict__ tgt,   // (512,)
    float* __restrict__ wap,        // (16, 512) per-jtile hardest-positive partial
    float* __restrict__ wan)        // (16, 512) per-jtile hardest-negative partial
{
    const int it = blockIdx.x;      // 0..31  (i-tile)
    const int jt = blockIdx.y;      // 0..15  (j-tile)
    const int t  = threadIdx.x;     // 0..255

    __shared__ float tile[(TI + TJ) * STRIDE];   // 48*260*4 = 49920 B
    __shared__ float sap[4][16], san[4][16];

    const int i0 = it * TI, j0 = jt * TJ;

    // Stage 48 rows (16 Xi + 32 Xj), coalesced float4 loads, padded LDS rows.
    #pragma unroll
    for (int k = 0; k < 12; ++k) {
        const int f = t + 256 * k;        // 0..3071 (3072 float4s total)
        const int r = f >> 6;             // local row 0..47
        const int c = (f & 63) << 2;      // float col, multiple of 4
        const int grow = (r < TI) ? (i0 + r) : (j0 + (r - TI));
        const float4 v = *(const float4*)(X + grow * D + c);
        *(float4*)(&tile[r * STRIDE + c]) = v;
    }
    __syncthreads();

    const int il = t & 15;          // anchor within tile
    const int jl = t >> 4;          // 0..15; this thread covers j = jl and jl+16
    const int ci  = tgt[i0 + il];
    const int cj0 = tgt[j0 + jl];
    const int cj1 = tgt[j0 + jl + 16];

    const float4* xi  = (const float4*)&tile[il * STRIDE];
    const float4* xj0 = (const float4*)&tile[(TI + jl) * STRIDE];
    const float4* xj1 = (const float4*)&tile[(TI + jl + 16) * STRIDE];

    float4 acc0 = {0.f, 0.f, 0.f, 0.f};
    float4 acc1 = {0.f, 0.f, 0.f, 0.f};

    #pragma unroll 8
    for (int d = 0; d < D / 4; ++d) {
        const float4 a = xi[d];           // 16 distinct rows/wave -> 2-way max (free)
        const float4 b = xj0[d];          // 4-address broadcast, distinct bank quads
        const float4 c = xj1[d];
        acc0.x += fabsf(a.x - b.x);  acc0.y += fabsf(a.y - b.y);
        acc0.z += fabsf(a.z - b.z);  acc0.w += fabsf(a.w - b.w);
        acc1.x += fabsf(a.x - c.x);  acc1.y += fabsf(a.y - c.y);
        acc1.z += fabsf(a.z - c.z);  acc1.w += fabsf(a.w - c.w);
    }
    const float d0 = (acc0.x + acc0.y + acc0.z + acc0.w) * (1.0f / (float)D);
    const float d1 = (acc1.x + acc1.y + acc1.z + acc1.w) * (1.0f / (float)D);

    float ap = fmaxf(cj0 == ci ? d0 : -INFINITY, cj1 == ci ? d1 : -INFINITY);
    float an = fminf(cj0 == ci ?  INFINITY : d0, cj1 == ci ?  INFINITY : d1);

    // Reduce over the 4 j-slots resident in this wave: lanes l, l^16, l^32, l^48.
    ap = fmaxf(ap, __shfl_xor(ap, 16, 64));
    an = fminf(an, __shfl_xor(an, 16, 64));
    ap = fmaxf(ap, __shfl_xor(ap, 32, 64));
    an = fminf(an, __shfl_xor(an, 32, 64));

    const int w = t >> 6, wl = t & 63;
    if (wl < 16) { sap[w][wl] = ap; san[w][wl] = an; }   // wl<16 => il == wl
    __syncthreads();

    if (t < 16) {
        const float A  = fmaxf(fmaxf(sap[0][t], sap[1][t]), fmaxf(sap[2][t], sap[3][t]));
        const float Nn = fminf(fminf(san[0][t], san[1][t]), fminf(san[2][t], san[3][t]));
        wap[jt * N + i0 + t] = A;
        wan[jt * N + i0 + t] = Nn;
    }
}

// Kernel 2: one block, 512 threads — combine 16 j-tile partials per row, hinge, mean.
__global__ __launch_bounds__(512) void triplet_final_kernel(
    const float* __restrict__ wap, const float* __restrict__ wan,
    float* __restrict__ out)
{
    const int t = threadIdx.x;      // row index 0..511
    float ap = -INFINITY, an = INFINITY;
    #pragma unroll
    for (int jt = 0; jt < 16; ++jt) {
        ap = fmaxf(ap, wap[jt * N + t]);    // coalesced across threads
        an = fminf(an, wan[jt * N + t]);
    }
    float v = fmaxf(ap - an + LOSS_MARGIN, 0.0f);
    #pragma unroll
    for (int off = 32; off >= 1; off >>= 1) v += __shfl_down(v, off, 64);
    __shared__ float s[8];
    if ((t & 63) == 0) s[t >> 6] = v;
    __syncthreads();
    if (t == 0) {
        float tot = 0.f;
        #pragma unroll
        for (int w = 0; w < 8; ++w) tot += s[w];
        out[0] = tot * (1.0f / (float)N);
    }
}

extern "C" void kernel_launch(void* const* d_in, const int* in_sizes, int n_in,
                              void* d_out, int out_size, void* d_ws, size_t ws_size,
                              hipStream_t stream) {
    const float* X   = (const float*)d_in[0];
    const int*   tgt = (const int*)d_in[1];
    float* out = (float*)d_out;
    float* wap = (float*)d_ws;          // 16*512 floats
    float* wan = wap + 16 * N;          // 16*512 floats

    dim3 grid(32, 16);
    triplet_tile_kernel<<<grid, 256, 0, stream>>>(X, tgt, wap, wan);
    triplet_final_kernel<<<1, 512, 0, stream>>>(wap, wan, out);
}